// Round 8
// baseline (243.884 us; speedup 1.0000x reference)
//
#include <hip/hip_runtime.h>
#include <hip/hip_bf16.h>
#include <math.h>

#define HH 512
#define WW 512
#define BB 8
#define TT 5
#define MID 16
#define HWSZ (HH*WW)      /* 262144 = 2^18 */
#define NPIX (BB*HWSZ)    /* 2097152 */

typedef __attribute__((ext_vector_type(8))) short bf16x8;
typedef __attribute__((ext_vector_type(4))) short bf16x4;
typedef __attribute__((ext_vector_type(4))) float f32x4;

#if __has_builtin(__builtin_amdgcn_exp2f)
#define EXP2F(x) __builtin_amdgcn_exp2f(x)
#else
#define EXP2F(x) exp2f(x)
#endif

#define LOG2E 1.4426950408889634f

// ---------- bf16 helpers ----------
__device__ inline unsigned short f2bf(float f){          // RNE (used in prep only)
  unsigned u = __float_as_uint(f);
  u = u + 0x7fffu + ((u >> 16) & 1u);
  return (unsigned short)(u >> 16);
}
// fast round-half-up pack of two floats -> bf16 pair (low16 = a, high16 = b)
__device__ inline unsigned packpair(float a, float b){
  unsigned ua = __float_as_uint(a) + 0x8000u;
  unsigned ub = __float_as_uint(b) + 0x8000u;
  return __builtin_amdgcn_perm(ub, ua, 0x07060302u);
}
__device__ inline float blo(unsigned u){ return __uint_as_float(u << 16); }
__device__ inline float bhi(unsigned u){ return __uint_as_float(u & 0xffff0000u); }

union U4B { uint4 u; bf16x8 h; };
union U2B { uint2 u; bf16x4 h; };

// ---------- consts layout (floats, in cst) ----------
// [162..177] bi1 (BN1 bias; BN1 scale folded into wsA1 weights)
// [242] bias*log2e
// [288..303] sc2a  [304..319] bi2a
// [320..335] sc3a  [336..351] bi3a

// ================= kernel 1: |raw_diff| accumulate + partial stats; block 2048 = weight prep =================
__global__ __launch_bounds__(256) void k_acc(const float* __restrict__ rd,
    float4* __restrict__ acc, float2* __restrict__ partial,
    const float* __restrict__ w1, const float* __restrict__ g1, const float* __restrict__ b1,
    const float* __restrict__ rm1, const float* __restrict__ rv1,
    const float* __restrict__ w2, const float* __restrict__ g2, const float* __restrict__ b2,
    const float* __restrict__ rm2, const float* __restrict__ rv2,
    const float* __restrict__ w3, const float* __restrict__ g3, const float* __restrict__ b3,
    const float* __restrict__ rm3, const float* __restrict__ rv3,
    const float* __restrict__ w4, const float* __restrict__ bias0,
    float* __restrict__ cst, uint2* __restrict__ wsA1,
    unsigned* __restrict__ wsB2, unsigned* __restrict__ wsB3, uint2* __restrict__ wsB4){
  int t = threadIdx.x;
  if (blockIdx.x == 2048){
    // ---- weight prep ----
    if (t == 0) cst[242] = bias0[0] * LOG2E;
    if (t < 16){
      float s1 = g1[t] * rsqrtf(rv1[t] + 1e-5f);
      cst[162 + t] = b1[t] - rm1[t] * s1;
      float c2 = g2[t] * rsqrtf(rv2[t] + 1e-5f);
      cst[288 + t] = c2; cst[304 + t] = b2[t] - rm2[t] * c2;
      float c3 = g3[t] * rsqrtf(rv3[t] + 1e-5f);
      cst[320 + t] = c3; cst[336 + t] = b3[t] - rm3[t] * c3;
    }
    // A-frag for conv1 16x16x16 MFMA: lane holds w1sc[o=lane&15][tap=(lane>>4)*4+j],
    // taps >= 9 ZERO; BN1 scale folded in.
    if (t < 64){
      int o = t & 15, qq = t >> 4;
      float s1o = g1[o] * rsqrtf(rv1[o] + 1e-5f);
      unsigned pk2[2];
      #pragma unroll
      for (int h = 0; h < 2; h++){
        unsigned lo = 0, hi = 0;
        int tp0 = qq*4 + 2*h, tp1 = tp0 + 1;
        if (tp0 < 9){ float sw = 0.f; for (int f = 0; f < TT; f++) sw += w1[o*45 + f*9 + tp0]; lo = f2bf(sw * s1o); }
        if (tp1 < 9){ float sw = 0.f; for (int f = 0; f < TT; f++) sw += w1[o*45 + f*9 + tp1]; hi = f2bf(sw * s1o); }
        pk2[h] = lo | (hi << 16);
      }
      wsA1[t] = make_uint2(pk2[0], pk2[1]);
    }
    // conv2/conv3 weight fragments for 16x16x32 MFMA (A operand); tap 9 ZERO.
    for (int it = 0; it < 5; it++){
      int idx = it * 256 + t;          // 0..1279
      int m = idx >> 8, rem = idx & 255;
      int L = rem >> 2, jj = rem & 3;
      int out = L & 15, q = L >> 4;
      unsigned v2 = 0, v3 = 0;
      #pragma unroll
      for (int h = 0; h < 2; h++){
        int j = 2*jj + h;
        int k = q*8 + j;
        int tap = 2*m + (k >> 4);
        int ci = k & 15;
        unsigned bv2 = 0, bv3 = 0;
        if (tap < 9){
          bv2 = f2bf(w2[out*144 + ci*9 + tap]);
          bv3 = f2bf(w3[out*144 + ci*9 + tap]);
        }
        v2 |= bv2 << (16*h);
        v3 |= bv3 << (16*h);
      }
      wsB2[idx] = v2; wsB3[idx] = v3;
    }
    // A-fragments for w4 16x16x16 MFMA (row = output o, k = channel), *log2e.
    if (t < 192){
      int c = t >> 6, L = t & 63;
      int n = L & 15, q = L >> 4;
      int o = c*16 + n;
      unsigned pk0 = 0, pk1 = 0;
      if (o < 45){
        unsigned b0 = f2bf(w4[o*16 + q*4 + 0] * LOG2E);
        unsigned b1v = f2bf(w4[o*16 + q*4 + 1] * LOG2E);
        unsigned b2v = f2bf(w4[o*16 + q*4 + 2] * LOG2E);
        unsigned b3v = f2bf(w4[o*16 + q*4 + 3] * LOG2E);
        pk0 = b0 | (b1v << 16);
        pk1 = b2v | (b3v << 16);
      }
      wsB4[c*64 + L] = make_uint2(pk0, pk1);
    }
    return;
  }
  // ---- acc path ----
  int gt = blockIdx.x * 256 + t;            // 0..524287
  int i = gt << 2;
  int b = i >> 18, p = i & (HWSZ - 1);
  const float* base = rd + (size_t)b * 4 * HWSZ + p;
  float4 f0 = *(const float4*)(base);
  float4 f1 = *(const float4*)(base + HWSZ);
  float4 f2 = *(const float4*)(base + 2*HWSZ);
  float4 f3 = *(const float4*)(base + 3*HWSZ);
  float4 s4;
  s4.x = fabsf(f0.x) + fabsf(f1.x) + fabsf(f2.x) + fabsf(f3.x);
  s4.y = fabsf(f0.y) + fabsf(f1.y) + fabsf(f2.y) + fabsf(f3.y);
  s4.z = fabsf(f0.z) + fabsf(f1.z) + fabsf(f2.z) + fabsf(f3.z);
  s4.w = fabsf(f0.w) + fabsf(f1.w) + fabsf(f2.w) + fabsf(f3.w);
  acc[gt] = s4;
  float s  = s4.x + s4.y + s4.z + s4.w;
  float s2 = s4.x*s4.x + s4.y*s4.y + s4.z*s4.z + s4.w*s4.w;
  #pragma unroll
  for (int off = 32; off; off >>= 1){
    s  += __shfl_down(s,  off);
    s2 += __shfl_down(s2, off);
  }
  __shared__ float ls[4], ls2[4];
  int lane = t & 63, wid = t >> 6;
  if (lane == 0){ ls[wid] = s; ls2[wid] = s2; }
  __syncthreads();
  if (t == 0)
    partial[blockIdx.x] = make_float2(ls[0]+ls[1]+ls[2]+ls[3],
                                      ls2[0]+ls2[1]+ls2[2]+ls2[3]);
}

// ---------- shared epilogue: BN/ReLU, w4 MFMA K=16, exp2-sigmoid, kern -> per-wave
// LDS, stride 96 with q-slot XOR swizzle keyed on (px>>2)&3 (reads use same key ->
// 16-bank spread, ~4-way; logical kvf order preserved). ----------
__device__ __forceinline__ void stage2_tail96(int g, f32x4 cc, float4 sc, float4 bi,
    float cb, const uint2 bw4[3], char* myL, int q, int col){
  float v0 = fmaxf(0.f, fmaf(cc[0], sc.x, bi.x));
  float v1 = fmaxf(0.f, fmaf(cc[1], sc.y, bi.y));
  float v2 = fmaxf(0.f, fmaf(cc[2], sc.z, bi.z));
  float v3 = fmaxf(0.f, fmaf(cc[3], sc.w, bi.w));
  U2B bb;
  bb.u.x = packpair(v0, v1);             // ch q*4+0, q*4+1 of pixel col
  bb.u.y = packpair(v2, v3);             // ch q*4+2, q*4+3
  int px = g*16 + col;
  char* wp = myL + px*96 + ((q ^ ((px >> 2) & 3)) << 3);
  #pragma unroll
  for (int c = 0; c < 3; c++){
    f32x4 aw = {cb, cb, cb, cb};
    U2B af; af.u = bw4[c];
    aw = __builtin_amdgcn_mfma_f32_16x16x16bf16_1k(af.h, bb.h, aw, 0, 0, 0);
    float k0 = fmaf(10.f, __builtin_amdgcn_rcpf(1.f + EXP2F(-aw[0])), 0.1f);
    float k1 = fmaf(10.f, __builtin_amdgcn_rcpf(1.f + EXP2F(-aw[1])), 0.1f);
    float k2 = fmaf(10.f, __builtin_amdgcn_rcpf(1.f + EXP2F(-aw[2])), 0.1f);
    float k3 = fmaf(10.f, __builtin_amdgcn_rcpf(1.f + EXP2F(-aw[3])), 0.1f);
    *(uint2*)(wp + c*32) = make_uint2(packpair(k0, k1), packpair(k2, k3));
  }
}

// ======== kernel 2: FUSED conv1+conv2+conv3+w4+sigmoid+enhance over 16x32 tiles ========
// All intermediates in LDS; h2 never touches HBM. LDS 81920 B = 2 blocks/CU:
//   [h2: 24x40x32B = 30720 | h1: 28x44x32B = 39424 | AT: 30x46x4B = 5520 | pad 560]
// kern (8 waves x 6144 B) aliases the dead h1/AT region in phase 3.
// conv zero-padding at image borders comes from masked h1/h2 writes (OOB -> 0),
// so conv2/conv3 need NO tap masking at all.
__global__ __launch_bounds__(512, 4) void k_fuse(const float* __restrict__ acc,
    const float2* __restrict__ partial, const float* __restrict__ C,
    const uint2* __restrict__ wsA1, const unsigned* __restrict__ wsB2,
    const unsigned* __restrict__ wsB3, const uint2* __restrict__ wsB4,
    const float* __restrict__ xal, float* __restrict__ out){
  __shared__ uint4 LDSQ[5120];            // 81920 B
  char* lds = (char*)LDSQ;
  char* h2b = lds;                        // 0..30720
  char* h1b = lds + 30720;                // ..70144
  float* ATf = (float*)(lds + 70144);     // 1380 floats + 140-dword zero pad
  float* rsf = (float*)lds;               // stats scratch (h2 area, dead until phase 2)

  int tid = threadIdx.x;
  int lane = tid & 63, wv = tid >> 6;
  int blk = blockIdx.x;                   // 16 tx | 32 ty | 8 b
  int tx0 = (blk & 15) << 5;
  int ty0 = ((blk >> 4) & 31) << 4;
  int b = blk >> 9;

  // ---- stats: reduce partial[2048] -> mean, inv (identical in every block) ----
  float s = 0.f, s2 = 0.f;
  #pragma unroll
  for (int j = 0; j < 2; j++){
    float4 v = ((const float4*)partial)[j*512 + tid];
    s += v.x + v.z; s2 += v.y + v.w;
  }
  #pragma unroll
  for (int off = 32; off; off >>= 1){
    s  += __shfl_down(s,  off);
    s2 += __shfl_down(s2, off);
  }
  if (lane == 0){ rsf[wv] = s; rsf[8 + wv] = s2; }
  __syncthreads();
  float S = 0.f, S2 = 0.f;
  #pragma unroll
  for (int c = 0; c < 8; c++){ S += rsf[c]; S2 += rsf[8 + c]; }
  float n = (float)NPIX;
  float mean = S / n;
  float var  = (S2 - n * mean * mean) / (n - 1.0f);
  float inv  = 1.f / (sqrtf(var) + 1e-6f);

  // ---- phase 0: stage normalized AT (30x46, halo 7) + zero conv1-garbage pad ----
  const float* ab = acc + ((size_t)b << 18);
  #pragma unroll
  for (int it = 0; it < 3; it++){
    int idx = it*512 + tid;
    if (idx < 1380){
      int r = (idx * 5699) >> 18;           // idx/46 exact for idx<1380
      int p = idx - r*46;
      int gy = ty0 - 7 + r, gx = tx0 - 7 + p;
      float v = 0.f;
      if ((unsigned)gy < HH && (unsigned)gx < WW)
        v = (ab[(gy << 9) + gx] - mean) * inv;
      ATf[idx] = v;
    } else if (idx < 1520){
      ATf[idx] = 0.f;                       // garbage-tap pad (reads reach idx 1515)
    }
  }
  __syncthreads();

  int col = lane & 15, q = lane >> 4;
  int chSel = q & 1;
  bool hiTap = (q >= 2);

  // ---- phase 1: conv1 via MFMA -> h1 (28x44; taps>=9 have zero weights, pad zeroed) ----
  {
    U2B a1; a1.u = wsA1[lane];
    float4 b1v = *(const float4*)&C[162 + q*4];
    f32x4 cinit = {b1v.x, b1v.y, b1v.z, b1v.w};
    int off_[4];
    #pragma unroll
    for (int j = 0; j < 4; j++){
      int tap = q*4 + j;
      int ky = (tap*11) >> 5;               // tap/3 exact for tap<16
      int kx = tap - 3*ky;
      off_[j] = (ky*46 + kx)*4;
    }
    const char* ATb = (const char*)ATf;
    for (int tt = wv; tt < 77; tt += 8){
      int p = tt*16 + col;                  // 0..1231
      int r2 = (p * 5958) >> 18;            // p/44 exact for p<1232
      int p2 = p - r2*44;
      int bofs = (r2*46 + p2)*4;
      float m0 = *(const float*)(ATb + bofs + off_[0]);
      float m1 = *(const float*)(ATb + bofs + off_[1]);
      float m2 = *(const float*)(ATb + bofs + off_[2]);
      float m3 = *(const float*)(ATb + bofs + off_[3]);
      U2B bfr;
      bfr.u.x = packpair(m0, m1);
      bfr.u.y = packpair(m2, m3);
      f32x4 z = __builtin_amdgcn_mfma_f32_16x16x16bf16_1k(a1.h, bfr.h, cinit, 0, 0, 0);
      int gy = ty0 + r2 - 6, gx = tx0 + p2 - 6;
      unsigned pk0 = 0u, pk1 = 0u;
      if (((unsigned)gy < HH) && ((unsigned)gx < WW)){
        pk0 = packpair(fmaxf(0.f, z[0]), fmaxf(0.f, z[1]));
        pk1 = packpair(fmaxf(0.f, z[2]), fmaxf(0.f, z[3]));
      }
      *(uint2*)(h1b + p*32 + q*8) = make_uint2(pk0, pk1);
    }
  }
  __syncthreads();

  // ---- phase 2: conv2 via MFMA -> h2 (24x40) ----
  {
    uint4 wfrag[5];
    #pragma unroll
    for (int m = 0; m < 5; m++) wfrag[m] = ((const uint4*)wsB2)[m*64 + lane];
    float4 sc = *(const float4*)&C[288 + q*4];
    float4 bi = *(const float4*)&C[304 + q*4];
    for (int tt = wv; tt < 60; tt += 8){
      int p = tt*16 + col;                  // 0..959
      int r3 = (p * 6554) >> 18;            // p/40 exact for p<960
      int p3 = p - r3*40;
      const char* bb0 = h1b + (unsigned)((r3*44 + p3) << 5) + (chSel << 4);
      f32x4 cc = {0.f, 0.f, 0.f, 0.f};
      #pragma unroll
      for (int m = 0; m < 5; m++){
        const int ta = 2*m, tb = (2*m + 1 > 8) ? 8 : (2*m + 1);  // tap9 -> tap8 (weight=0)
        int dy = (hiTap ? tb/3 : ta/3) - 1;
        int dx = (hiTap ? tb%3 : ta%3) - 1;
        int imm = (((2 + 2*dy)*44) + (2 + 2*dx)) << 5;  // in [0,5760]
        U4B bv; bv.u = *(const uint4*)(bb0 + imm);
        U4B wb; wb.u = wfrag[m];
        cc = __builtin_amdgcn_mfma_f32_16x16x32_bf16(wb.h, bv.h, cc, 0, 0, 0);
      }
      float v0 = fmaxf(0.f, fmaf(cc[0], sc.x, bi.x));
      float v1 = fmaxf(0.f, fmaf(cc[1], sc.y, bi.y));
      float v2 = fmaxf(0.f, fmaf(cc[2], sc.z, bi.z));
      float v3 = fmaxf(0.f, fmaf(cc[3], sc.w, bi.w));
      int gy = ty0 + r3 - 4, gx = tx0 + p3 - 4;
      unsigned pk0 = 0u, pk1 = 0u;
      if (((unsigned)gy < HH) && ((unsigned)gx < WW)){
        pk0 = packpair(v0, v1);
        pk1 = packpair(v2, v3);
      }
      *(uint2*)(h2b + p*32 + q*8) = make_uint2(pk0, pk1);
    }
  }
  __syncthreads();   // h1/AT dead; kern may alias them

  // ---- phase 3: conv3 (LDS h2, no masking) + w4 + sigmoid -> kern; then enhance ----
  uint4 wfrag3[5];
  #pragma unroll
  for (int m = 0; m < 5; m++) wfrag3[m] = ((const uint4*)wsB3)[m*64 + lane];
  uint2 bw4[3];
  #pragma unroll
  for (int c = 0; c < 3; c++) bw4[c] = wsB4[c*64 + lane];
  float4 sc3 = *(const float4*)&C[320 + q*4];
  float4 bi3 = *(const float4*)&C[336 + q*4];
  float cb = C[242];                        // bias*log2e
  char* myL = lds + 30720 + wv*6144;
  int rbase = wv*2;
  bool ySlow = (ty0 == 0 && wv == 0) || (ty0 == 496 && wv == 7);
  int y  = ty0 + rbase + (lane >> 5);
  int px = tx0 + (lane & 31);

  // prefetch stage-3 patches (interior-y waves); latency hides under conv3/w4 below
  float xv[TT][9];
  if (!ySlow){
    const char* p0 = (const char*)xal + (((size_t)(b*TT)) << 20)
                   + (unsigned)(y << 11) + (px << 2);
    #pragma unroll
    for (int t = 0; t < TT; t++){
      const char* pc = p0 + (size_t)t * (HWSZ*4);
      xv[t][0] = *(const float*)(pc - 2052);
      xv[t][1] = *(const float*)(pc - 2048);
      xv[t][2] = *(const float*)(pc - 2044);
      xv[t][3] = *(const float*)(pc - 4);
      xv[t][4] = *(const float*)(pc);
      xv[t][5] = *(const float*)(pc + 4);
      xv[t][6] = *(const float*)(pc + 2044);
      xv[t][7] = *(const float*)(pc + 2048);
      xv[t][8] = *(const float*)(pc + 2052);
    }
  }

  #pragma unroll
  for (int g = 0; g < 4; g++){
    int row = rbase + (g >> 1);
    int x0 = (g & 1) << 4;
    const char* bb0 = h2b + (unsigned)((row*40 + x0 + col) << 5) + (chSel << 4);
    f32x4 cc = {0.f, 0.f, 0.f, 0.f};
    #pragma unroll
    for (int m = 0; m < 5; m++){
      const int ta = 2*m, tb = (2*m + 1 > 8) ? 8 : (2*m + 1);
      int dy = (hiTap ? tb/3 : ta/3) - 1;
      int dx = (hiTap ? tb%3 : ta%3) - 1;
      int imm = (((4 + 4*dy)*40) + (4 + 4*dx)) << 5;   // in [0,10496]
      U4B bv; bv.u = *(const uint4*)(bb0 + imm);
      U4B wb; wb.u = wfrag3[m];
      cc = __builtin_amdgcn_mfma_f32_16x16x32_bf16(wb.h, bv.h, cc, 0, 0, 0);
    }
    stage2_tail96(g, cc, sc3, bi3, cb, bw4, myL, q, col);
  }

  // ---- kern -> registers (swizzled addresses, logical order preserved) ----
  unsigned kvf[24];
  {
    int k3 = (lane >> 2) & 3;
    const char* kp = myL + lane*96;
    #pragma unroll
    for (int c = 0; c < 3; c++){
      #pragma unroll
      for (int qq = 0; qq < 4; qq++){
        uint2 u = *(const uint2*)(kp + c*32 + ((qq ^ k3) << 3));
        kvf[(c*4 + qq)*2]     = u.x;
        kvf[(c*4 + qq)*2 + 1] = u.y;
      }
    }
  }

  // ---- stage 3: 45 kern x patch FMAs ----
  if (!ySlow){
    bool xe = (tx0 == 0) || (tx0 == 480);
    if (xe){
      bool mxl = (px > 0), mxr = (px < 511);
      #pragma unroll
      for (int t = 0; t < TT; t++){
        float ov = 0.f;
        #pragma unroll
        for (int k = 0; k < 9; k++){
          int nn = t*9 + k;
          unsigned u = kvf[nn >> 1];
          float kf = (nn & 1) ? bhi(u) : blo(u);
          if (k % 3 == 0)      kf = mxl ? kf : 0.f;
          else if (k % 3 == 2) kf = mxr ? kf : 0.f;
          ov = fmaf(kf, xv[t][k], ov);
        }
        out[((size_t)(b*TT + t) << 18) + (y << 9) + px] = ov;
      }
    } else {
      #pragma unroll
      for (int t = 0; t < TT; t++){
        float ov = 0.f;
        #pragma unroll
        for (int k = 0; k < 9; k++){
          int nn = t*9 + k;
          unsigned u = kvf[nn >> 1];
          float kf = (nn & 1) ? bhi(u) : blo(u);
          ov = fmaf(kf, xv[t][k], ov);
        }
        out[((size_t)(b*TT + t) << 18) + (y << 9) + px] = ov;
      }
    }
  } else {
    // y-edge waves (rows 0,1 or 510,511): fully masked loads
    bool mxl = (px > 0), mxr = (px < 511), mym = (y > 0), myp = (y < 511);
    bool msk[9] = { mym&&mxl, mym, mym&&mxr,
                    mxl,      true, mxr,
                    myp&&mxl, myp, myp&&mxr };
    int rowm = mym ? -2048 : 0;
    int rowp = myp ?  2048 : 0;
    int loff = mxl ? -4 : 0;
    int roff = mxr ?  4 : 0;
    const char* base0 = (const char*)(xal + ((size_t)(b*TT) << 18) + (y << 9) + px);
    #pragma unroll
    for (int t = 0; t < TT; t++){
      const char* pc = base0 + (size_t)t * (HWSZ*4);
      const char* pm = pc + rowm;
      const char* pp = pc + rowp;
      float zv[9];
      zv[0] = *(const float*)(pm + loff);
      zv[1] = *(const float*)(pm);
      zv[2] = *(const float*)(pm + roff);
      zv[3] = *(const float*)(pc + loff);
      zv[4] = *(const float*)(pc);
      zv[5] = *(const float*)(pc + roff);
      zv[6] = *(const float*)(pp + loff);
      zv[7] = *(const float*)(pp);
      zv[8] = *(const float*)(pp + roff);
      float ov = 0.f;
      #pragma unroll
      for (int k = 0; k < 9; k++){
        int nn = t*9 + k;
        unsigned u = kvf[nn >> 1];
        float kf = (nn & 1) ? bhi(u) : blo(u);
        float kern = msk[k] ? kf : 0.f;
        ov = fmaf(kern, zv[k], ov);
      }
      out[((size_t)(b*TT + t) << 18) + (y << 9) + px] = ov;
    }
  }
}

extern "C" void kernel_launch(void* const* d_in, const int* in_sizes, int n_in,
                              void* d_out, int out_size, void* d_ws, size_t ws_size,
                              hipStream_t stream){
  const float* xal = (const float*)d_in[0];
  const float* rd  = (const float*)d_in[1];
  const float* w1  = (const float*)d_in[2];
  const float* g1  = (const float*)d_in[3];
  const float* b1  = (const float*)d_in[4];
  const float* rm1 = (const float*)d_in[5];
  const float* rv1 = (const float*)d_in[6];
  const float* w2  = (const float*)d_in[7];
  const float* g2  = (const float*)d_in[8];
  const float* b2  = (const float*)d_in[9];
  const float* rm2 = (const float*)d_in[10];
  const float* rv2 = (const float*)d_in[11];
  const float* w3  = (const float*)d_in[12];
  const float* g3  = (const float*)d_in[13];
  const float* b3  = (const float*)d_in[14];
  const float* rm3 = (const float*)d_in[15];
  const float* rv3 = (const float*)d_in[16];
  const float* w4  = (const float*)d_in[17];
  const float* bias= (const float*)d_in[18];
  float* out = (float*)d_out;

  char* ws = (char*)d_ws;
  float2*   partial = (float2*)ws;                    // 16 KB
  float*    cst   = (float*)(ws + 16384);             // 352 floats used
  unsigned* wsB2  = (unsigned*)(ws + 32768);          // 5 KB
  unsigned* wsB3  = (unsigned*)(ws + 40960);          // 5 KB
  uint2*    wsB4  = (uint2*)(ws + 49152);             // 1.5 KB
  uint2*    wsA1  = (uint2*)(ws + 57344);             // 512 B
  float*    acc   = (float*)(ws + 65536);             // 8 MB (h2 eliminated)

  k_acc<<<2049, 256, 0, stream>>>(rd, (float4*)acc, partial,
                                  w1, g1, b1, rm1, rv1,
                                  w2, g2, b2, rm2, rv2,
                                  w3, g3, b3, rm3, rv3,
                                  w4, bias, cst, wsA1, wsB2, wsB3, wsB4);
  k_fuse<<<4096, 512, 0, stream>>>(acc, partial, cst, wsA1, wsB2, wsB3, wsB4,
                                   xal, out);
}